// Round 1
// baseline (1855.988 us; speedup 1.0000x reference)
//
#include <hip/hip_runtime.h>
#include <math.h>

#define TOK   8192
#define DIM   256
#define NH    8
#define HDIM  32
#define FFD   1024
#define NE    8
#define NL    2
#define NOUT  1000
#define NSLOT 16384   // TOK*2

// ---------------- workspace layout (float units) ----------------
#define WS_X     ((size_t)0)
#define WS_LN    (WS_X    + (size_t)TOK*DIM)       // 2,097,152
#define WS_QKV   (WS_LN   + (size_t)TOK*DIM)       // 4,194,304
#define WS_H     (WS_QKV  + (size_t)TOK*3*DIM)     // 10,485,760  (NSLOT x 256 chunk)
#define WS_SOUT  (WS_H    + (size_t)NSLOT*256)     // 14,680,064  (NSLOT x 256)
#define WS_GV    (WS_SOUT + (size_t)NSLOT*256)     // 18,874,368  (TOK*2 gate weights)
#define WS_PP    (WS_GV   + (size_t)TOK*2)         // pool partials 8*32*256
#define WS_POOL  (WS_PP   + (size_t)8*32*256)
#define WS_INT   (WS_POOL + (size_t)8*256)         // int region from here

// int region layout (int32 indices)
#define IB_COUNTS   0     // [8]
#define IB_NTILES   8     // [1]
#define IB_OFFS     16    // [8]
#define IB_CURS     24    // [8]
#define IB_TILE_E   32    // [288]
#define IB_TILE_R0  320   // [288]
#define IB_TILE_RE  608   // [288]
#define IB_GIDX     896   // [TOK*2]
#define IB_SPOS     17280 // [TOK*2]
#define IB_STOK     33664 // [NSLOT]

__device__ __forceinline__ float gelu_exact(float v) {
    return 0.5f * v * (1.0f + erff(v * 0.70710678118654752f));
}

// ---------------- LayerNorm: one wave per token ----------------
__global__ __launch_bounds__(256) void ln_kernel(const float* __restrict__ x,
                                                 float* __restrict__ out,
                                                 const float* __restrict__ g,
                                                 const float* __restrict__ b) {
    int wave = threadIdx.x >> 6;
    int lane = threadIdx.x & 63;
    int t = blockIdx.x * 4 + wave;
    const float* xp = x + (size_t)t * DIM;
    float4 v = *(const float4*)&xp[lane * 4];
    float s = v.x + v.y + v.z + v.w;
    #pragma unroll
    for (int off = 32; off; off >>= 1) s += __shfl_xor(s, off);
    float mean = s * (1.0f / 256.0f);
    float dx = v.x - mean, dy = v.y - mean, dz = v.z - mean, dw = v.w - mean;
    float vs = dx * dx + dy * dy + dz * dz + dw * dw;
    #pragma unroll
    for (int off = 32; off; off >>= 1) vs += __shfl_xor(vs, off);
    float inv = rsqrtf(vs * (1.0f / 256.0f) + 1e-5f);
    float4 gg = *(const float4*)&g[lane * 4];
    float4 bb = *(const float4*)&b[lane * 4];
    float4 o;
    o.x = dx * inv * gg.x + bb.x;
    o.y = dy * inv * gg.y + bb.y;
    o.z = dz * inv * gg.z + bb.z;
    o.w = dw * inv * gg.w + bb.w;
    *(float4*)&out[(size_t)t * DIM + lane * 4] = o;
}

// ---------------- dense GEMM: C[M,N] = A[M,256] @ W[256,N] + bias (+residual) ----------------
template <bool RESIDUAL>
__global__ __launch_bounds__(256) void gemm_bias(const float* __restrict__ A,
                                                 const float* __restrict__ W,
                                                 const float* __restrict__ bias,
                                                 float* __restrict__ C, int N) {
    __shared__ float As[64][36];
    __shared__ float Ws[32][68];
    int tid = threadIdx.x;
    int tx = tid & 15, ty = tid >> 4;
    int row0 = blockIdx.x * 64, col0 = blockIdx.y * 64;
    float acc[4][4] = {};
    for (int k0 = 0; k0 < 256; k0 += 32) {
        #pragma unroll
        for (int l = 0; l < 2; ++l) {
            int lin = tid + l * 256;          // float4 index among 512
            int r = lin >> 3, c = (lin & 7) << 2;
            float4 v = *(const float4*)&A[(size_t)(row0 + r) * 256 + k0 + c];
            *(float4*)&As[r][c] = v;
        }
        #pragma unroll
        for (int l = 0; l < 2; ++l) {
            int lin = tid + l * 256;
            int r = lin >> 4, c = (lin & 15) << 2;
            float4 v = *(const float4*)&W[(size_t)(k0 + r) * N + col0 + c];
            *(float4*)&Ws[r][c] = v;
        }
        __syncthreads();
        #pragma unroll
        for (int kk = 0; kk < 32; ++kk) {
            float a[4], bfr[4];
            #pragma unroll
            for (int i = 0; i < 4; ++i) a[i] = As[ty * 4 + i][kk];
            #pragma unroll
            for (int j = 0; j < 4; ++j) bfr[j] = Ws[kk][tx * 4 + j];
            #pragma unroll
            for (int i = 0; i < 4; ++i)
                #pragma unroll
                for (int j = 0; j < 4; ++j) acc[i][j] += a[i] * bfr[j];
        }
        __syncthreads();
    }
    #pragma unroll
    for (int i = 0; i < 4; ++i) {
        int r = row0 + ty * 4 + i;
        #pragma unroll
        for (int j = 0; j < 4; ++j) {
            int c = col0 + tx * 4 + j;
            float v = acc[i][j] + bias[c];
            if (RESIDUAL) v += C[(size_t)r * N + c];
            C[(size_t)r * N + c] = v;
        }
    }
}

// ---------------- attention: thread per q-row, online softmax ----------------
__global__ __launch_bounds__(256) void attention_kernel(const float* __restrict__ qkv,
                                                        float* __restrict__ obuf) {
    int b = blockIdx.z, hh = blockIdx.y, qt = blockIdx.x;
    int sq = qt * 256 + threadIdx.x;
    const float* base = qkv + (size_t)b * 1024 * 768;
    float q[32];
    const float* qptr = base + (size_t)sq * 768 + hh * 32;
    #pragma unroll
    for (int i = 0; i < 8; ++i) {
        float4 v = *(const float4*)(qptr + i * 4);
        q[4 * i] = v.x; q[4 * i + 1] = v.y; q[4 * i + 2] = v.z; q[4 * i + 3] = v.w;
    }
    float m = -1e30f, lsum = 0.0f;
    float o[32];
    #pragma unroll
    for (int i = 0; i < 32; ++i) o[i] = 0.0f;
    __shared__ float Kt[64][32];
    __shared__ float Vt[64][32];
    const float scale = 0.17677669529663687f;
    for (int kt = 0; kt < 16; ++kt) {
        __syncthreads();
        #pragma unroll
        for (int l = 0; l < 2; ++l) {
            int f4 = threadIdx.x + l * 256;   // 512 float4 per matrix
            int r = f4 >> 3, c = (f4 & 7) << 2;
            const float* kp = base + (size_t)(kt * 64 + r) * 768 + 256 + hh * 32 + c;
            *(float4*)&Kt[r][c] = *(const float4*)kp;
            const float* vp = base + (size_t)(kt * 64 + r) * 768 + 512 + hh * 32 + c;
            *(float4*)&Vt[r][c] = *(const float4*)vp;
        }
        __syncthreads();
        for (int j = 0; j < 64; ++j) {
            float s = 0.0f;
            #pragma unroll
            for (int d4 = 0; d4 < 8; ++d4) {
                float4 kk = *(const float4*)&Kt[j][d4 * 4];
                s += q[4 * d4] * kk.x + q[4 * d4 + 1] * kk.y + q[4 * d4 + 2] * kk.z + q[4 * d4 + 3] * kk.w;
            }
            s *= scale;
            if (s > m) {
                float corr = __expf(m - s);
                lsum *= corr;
                #pragma unroll
                for (int d = 0; d < 32; ++d) o[d] *= corr;
                m = s;
            }
            float p = __expf(s - m);
            lsum += p;
            #pragma unroll
            for (int d4 = 0; d4 < 8; ++d4) {
                float4 vv = *(const float4*)&Vt[j][d4 * 4];
                o[4 * d4]     += p * vv.x;
                o[4 * d4 + 1] += p * vv.y;
                o[4 * d4 + 2] += p * vv.z;
                o[4 * d4 + 3] += p * vv.w;
            }
        }
    }
    float inv = 1.0f / lsum;
    float* op = obuf + (size_t)(b * 1024 + sq) * 256 + hh * 32;
    #pragma unroll
    for (int i = 0; i < 8; ++i) {
        float4 v;
        v.x = o[4 * i] * inv; v.y = o[4 * i + 1] * inv;
        v.z = o[4 * i + 2] * inv; v.w = o[4 * i + 3] * inv;
        *(float4*)(op + i * 4) = v;
    }
}

// ---------------- gate + top2 ----------------
__global__ __launch_bounds__(256) void gate_topk(const float* __restrict__ lnb,
                                                 const float* __restrict__ gw,
                                                 const float* __restrict__ gb,
                                                 float* __restrict__ gv, int* __restrict__ ib) {
    int t = blockIdx.x * blockDim.x + threadIdx.x;
    const float* x = lnb + (size_t)t * DIM;
    float g[8];
    #pragma unroll
    for (int e = 0; e < 8; ++e) g[e] = gb[e];
    for (int d4 = 0; d4 < 64; ++d4) {
        float4 xv = *(const float4*)&x[d4 * 4];
        const float* w0 = gw + (size_t)(d4 * 4) * 8;
        #pragma unroll
        for (int e = 0; e < 8; ++e) g[e] += xv.x * w0[e];
        #pragma unroll
        for (int e = 0; e < 8; ++e) g[e] += xv.y * w0[8 + e];
        #pragma unroll
        for (int e = 0; e < 8; ++e) g[e] += xv.z * w0[16 + e];
        #pragma unroll
        for (int e = 0; e < 8; ++e) g[e] += xv.w * w0[24 + e];
    }
    int i0 = 0; float s0 = g[0];
    #pragma unroll
    for (int e = 1; e < 8; ++e) if (g[e] > s0) { s0 = g[e]; i0 = e; }
    int i1 = -1; float s1 = -1e30f;
    #pragma unroll
    for (int e = 0; e < 8; ++e) if (e != i0 && g[e] > s1) { s1 = g[e]; i1 = e; }
    float e1 = __expf(s1 - s0);
    float w0v = 1.0f / (1.0f + e1);
    float w1v = e1 / (1.0f + e1);
    gv[2 * t] = w0v; gv[2 * t + 1] = w1v;
    ib[IB_GIDX + 2 * t] = i0; ib[IB_GIDX + 2 * t + 1] = i1;
    atomicAdd(&ib[IB_COUNTS + i0], 1);
    atomicAdd(&ib[IB_COUNTS + i1], 1);
}

// ---------------- scan + tile table (single thread) ----------------
__global__ void scan_tiles(int* ib) {
    if (threadIdx.x != 0 || blockIdx.x != 0) return;
    int off = 0, idx = 0;
    for (int e = 0; e < 8; ++e) {
        ib[IB_OFFS + e] = off;
        ib[IB_CURS + e] = off;
        int n = ib[IB_COUNTS + e];
        int nt = (n + 63) >> 6;
        for (int i = 0; i < nt; ++i) {
            ib[IB_TILE_E + idx] = e;
            ib[IB_TILE_R0 + idx] = off + i * 64;
            int re = off + ((i + 1) * 64 < n ? (i + 1) * 64 : n);
            ib[IB_TILE_RE + idx] = re;
            ++idx;
        }
        off += n;
    }
    ib[IB_NTILES] = idx;
}

// ---------------- scatter to slots ----------------
__global__ __launch_bounds__(256) void scatter_slots(int* ib) {
    int t = blockIdx.x * blockDim.x + threadIdx.x;
    #pragma unroll
    for (int k = 0; k < 2; ++k) {
        int e = ib[IB_GIDX + 2 * t + k];
        int pos = atomicAdd(&ib[IB_CURS + e], 1);
        ib[IB_STOK + pos] = t;
        ib[IB_SPOS + 2 * t + k] = pos;
    }
}

// ---------------- grouped FFN1: h = gelu(X[slots] @ W1[:, c0:c0+256] + b1) ----------------
__global__ __launch_bounds__(256) void ffn1_kernel(const float* __restrict__ lnb,
                                                   const float* __restrict__ w1l,
                                                   const float* __restrict__ b1l,
                                                   float* __restrict__ h,
                                                   const int* __restrict__ ib, int c0) {
    int tileIdx = blockIdx.x;
    if (tileIdx >= ib[IB_NTILES]) return;
    int e = ib[IB_TILE_E + tileIdx];
    int row0 = ib[IB_TILE_R0 + tileIdx];
    int rowend = ib[IB_TILE_RE + tileIdx];
    __shared__ float As[64][36];
    __shared__ float Ws[32][68];
    __shared__ int tok[64];
    int tid = threadIdx.x;
    if (tid < 64) {
        int sr = row0 + tid;
        tok[tid] = (sr < rowend) ? ib[IB_STOK + sr] : ib[IB_STOK + row0];
    }
    __syncthreads();
    const float* W1 = w1l + (size_t)e * DIM * FFD;
    int tx = tid & 15, ty = tid >> 4;
    int coln0 = blockIdx.y * 64;
    float acc[4][4] = {};
    for (int k0 = 0; k0 < 256; k0 += 32) {
        #pragma unroll
        for (int l = 0; l < 2; ++l) {
            int lin = tid + l * 256;
            int r = lin >> 3, c = (lin & 7) << 2;
            float4 v = *(const float4*)&lnb[(size_t)tok[r] * 256 + k0 + c];
            *(float4*)&As[r][c] = v;
        }
        #pragma unroll
        for (int l = 0; l < 2; ++l) {
            int lin = tid + l * 256;
            int r = lin >> 4, c = (lin & 15) << 2;
            float4 v = *(const float4*)&W1[(size_t)(k0 + r) * FFD + c0 + coln0 + c];
            *(float4*)&Ws[r][c] = v;
        }
        __syncthreads();
        #pragma unroll
        for (int kk = 0; kk < 32; ++kk) {
            float a[4], bfr[4];
            #pragma unroll
            for (int i = 0; i < 4; ++i) a[i] = As[ty * 4 + i][kk];
            #pragma unroll
            for (int j = 0; j < 4; ++j) bfr[j] = Ws[kk][tx * 4 + j];
            #pragma unroll
            for (int i = 0; i < 4; ++i)
                #pragma unroll
                for (int j = 0; j < 4; ++j) acc[i][j] += a[i] * bfr[j];
        }
        __syncthreads();
    }
    #pragma unroll
    for (int i = 0; i < 4; ++i) {
        int sr = row0 + ty * 4 + i;
        if (sr < rowend) {
            #pragma unroll
            for (int j = 0; j < 4; ++j) {
                int cl = coln0 + tx * 4 + j;          // chunk-local col
                float v = acc[i][j] + b1l[(size_t)e * FFD + c0 + cl];
                h[(size_t)sr * 256 + cl] = gelu_exact(v);
            }
        }
    }
}

// ---------------- grouped FFN2: slotout (+)= h @ W2[c0:c0+256, :] (+ b2 on first chunk) ----------------
__global__ __launch_bounds__(256) void ffn2_kernel(const float* __restrict__ h,
                                                   const float* __restrict__ w2l,
                                                   const float* __restrict__ b2l,
                                                   float* __restrict__ sout,
                                                   const int* __restrict__ ib, int c0) {
    int tileIdx = blockIdx.x;
    if (tileIdx >= ib[IB_NTILES]) return;
    int e = ib[IB_TILE_E + tileIdx];
    int row0 = ib[IB_TILE_R0 + tileIdx];
    int rowend = ib[IB_TILE_RE + tileIdx];
    __shared__ float As[64][36];
    __shared__ float Ws[32][68];
    const float* W2 = w2l + (size_t)e * FFD * DIM;
    int tid = threadIdx.x;
    int tx = tid & 15, ty = tid >> 4;
    int coln0 = blockIdx.y * 64;
    float acc[4][4] = {};
    for (int k0 = 0; k0 < 256; k0 += 32) {
        #pragma unroll
        for (int l = 0; l < 2; ++l) {
            int lin = tid + l * 256;
            int r = lin >> 3, c = (lin & 7) << 2;
            float4 v = *(const float4*)&h[(size_t)(row0 + r) * 256 + k0 + c];
            *(float4*)&As[r][c] = v;
        }
        #pragma unroll
        for (int l = 0; l < 2; ++l) {
            int lin = tid + l * 256;
            int r = lin >> 4, c = (lin & 15) << 2;
            float4 v = *(const float4*)&W2[(size_t)(c0 + k0 + r) * DIM + coln0 + c];
            *(float4*)&Ws[r][c] = v;
        }
        __syncthreads();
        #pragma unroll
        for (int kk = 0; kk < 32; ++kk) {
            float a[4], bfr[4];
            #pragma unroll
            for (int i = 0; i < 4; ++i) a[i] = As[ty * 4 + i][kk];
            #pragma unroll
            for (int j = 0; j < 4; ++j) bfr[j] = Ws[kk][tx * 4 + j];
            #pragma unroll
            for (int i = 0; i < 4; ++i)
                #pragma unroll
                for (int j = 0; j < 4; ++j) acc[i][j] += a[i] * bfr[j];
        }
        __syncthreads();
    }
    #pragma unroll
    for (int i = 0; i < 4; ++i) {
        int sr = row0 + ty * 4 + i;
        if (sr < rowend) {
            #pragma unroll
            for (int j = 0; j < 4; ++j) {
                int n = coln0 + tx * 4 + j;
                size_t oidx = (size_t)sr * 256 + n;
                if (c0 == 0) sout[oidx] = acc[i][j] + b2l[(size_t)e * DIM + n];
                else         sout[oidx] += acc[i][j];
            }
        }
    }
}

// ---------------- gather: x += g0*sout[p0] + g1*sout[p1] ----------------
__global__ __launch_bounds__(64) void moe_gather(float* __restrict__ xb,
                                                 const float* __restrict__ sout,
                                                 const float* __restrict__ gv,
                                                 const int* __restrict__ ib) {
    int t = blockIdx.x;
    int d = threadIdx.x * 4;
    int p0 = ib[IB_SPOS + 2 * t], p1 = ib[IB_SPOS + 2 * t + 1];
    float g0 = gv[2 * t], g1 = gv[2 * t + 1];
    float4 xv = *(float4*)&xb[(size_t)t * 256 + d];
    float4 s0 = *(const float4*)&sout[(size_t)p0 * 256 + d];
    float4 s1 = *(const float4*)&sout[(size_t)p1 * 256 + d];
    xv.x += g0 * s0.x + g1 * s1.x;
    xv.y += g0 * s0.y + g1 * s1.y;
    xv.z += g0 * s0.z + g1 * s1.z;
    xv.w += g0 * s0.w + g1 * s1.w;
    *(float4*)&xb[(size_t)t * 256 + d] = xv;
}

// ---------------- pooling ----------------
__global__ __launch_bounds__(256) void pool1(const float* __restrict__ xb, float* __restrict__ pp) {
    int b = blockIdx.x, ch = blockIdx.y, d = threadIdx.x;
    float s = 0.0f;
    for (int i = 0; i < 32; ++i) s += xb[((size_t)b * 1024 + ch * 32 + i) * 256 + d];
    pp[(size_t)(b * 32 + ch) * 256 + d] = s;
}
__global__ __launch_bounds__(256) void pool2(const float* __restrict__ pp, float* __restrict__ pool) {
    int b = blockIdx.x, d = threadIdx.x;
    float s = 0.0f;
    for (int c = 0; c < 32; ++c) s += pp[(size_t)(b * 32 + c) * 256 + d];
    pool[(size_t)b * 256 + d] = s * (1.0f / 1024.0f);
}

// ---------------- head ----------------
__global__ __launch_bounds__(256) void head_kernel(const float* __restrict__ pool,
                                                   const float* __restrict__ hw,
                                                   const float* __restrict__ hb,
                                                   float* __restrict__ out) {
    __shared__ float P[2048];
    int tid = threadIdx.x;
    for (int i = tid; i < 2048; i += 256) P[i] = pool[i];
    __syncthreads();
    int j = blockIdx.x * 256 + tid;
    if (j >= NOUT) return;
    float acc[8] = {};
    for (int d = 0; d < 256; ++d) {
        float w = hw[(size_t)d * NOUT + j];
        #pragma unroll
        for (int b = 0; b < 8; ++b) acc[b] += P[b * 256 + d] * w;
    }
    #pragma unroll
    for (int b = 0; b < 8; ++b) out[(size_t)b * NOUT + j] = acc[b] + hb[j];
}

extern "C" void kernel_launch(void* const* d_in, const int* in_sizes, int n_in,
                              void* d_out, int out_size, void* d_ws, size_t ws_size,
                              hipStream_t stream) {
    const float* x      = (const float*)d_in[0];
    const float* qkv_w  = (const float*)d_in[1];
    const float* qkv_b  = (const float*)d_in[2];
    const float* attn_w = (const float*)d_in[3];
    const float* attn_b = (const float*)d_in[4];
    const float* gate_w = (const float*)d_in[5];
    const float* gate_b = (const float*)d_in[6];
    const float* e_w1   = (const float*)d_in[7];
    const float* e_b1   = (const float*)d_in[8];
    const float* e_w2   = (const float*)d_in[9];
    const float* e_b2   = (const float*)d_in[10];
    const float* ln1_g  = (const float*)d_in[11];
    const float* ln1_b  = (const float*)d_in[12];
    const float* ln2_g  = (const float*)d_in[13];
    const float* ln2_b  = (const float*)d_in[14];
    const float* head_w = (const float*)d_in[15];
    const float* head_b = (const float*)d_in[16];
    float* out = (float*)d_out;
    float* wsf = (float*)d_ws;

    float* xb   = wsf + WS_X;
    float* lnb  = wsf + WS_LN;
    float* qkvb = wsf + WS_QKV;
    float* hb   = wsf + WS_H;
    float* sob  = wsf + WS_SOUT;
    float* gv   = wsf + WS_GV;
    float* pp   = wsf + WS_PP;
    float* pool = wsf + WS_POOL;
    int*   ib   = (int*)(wsf + WS_INT);

    hipMemcpyAsync(xb, x, (size_t)TOK * DIM * sizeof(float), hipMemcpyDeviceToDevice, stream);

    for (int l = 0; l < NL; ++l) {
        // --- attention block ---
        ln_kernel<<<TOK / 4, 256, 0, stream>>>(xb, lnb, ln1_g, ln1_b);
        gemm_bias<false><<<dim3(TOK / 64, 12), 256, 0, stream>>>(
            lnb, qkv_w + (size_t)l * DIM * 3 * DIM, qkv_b + (size_t)l * 3 * DIM, qkvb, 768);
        attention_kernel<<<dim3(4, NH, 8), 256, 0, stream>>>(qkvb, lnb);
        gemm_bias<true><<<dim3(TOK / 64, 4), 256, 0, stream>>>(
            lnb, attn_w + (size_t)l * DIM * DIM, attn_b + (size_t)l * DIM, xb, 256);

        // --- MoE block ---
        ln_kernel<<<TOK / 4, 256, 0, stream>>>(xb, lnb, ln2_g, ln2_b);
        hipMemsetAsync(ib, 0, 64, stream);
        gate_topk<<<TOK / 256, 256, 0, stream>>>(
            lnb, gate_w + (size_t)l * DIM * NE, gate_b + (size_t)l * NE, gv, ib);
        scan_tiles<<<1, 64, 0, stream>>>(ib);
        scatter_slots<<<TOK / 256, 256, 0, stream>>>(ib);
        for (int c = 0; c < 4; ++c) {
            ffn1_kernel<<<dim3(272, 4), 256, 0, stream>>>(
                lnb, e_w1 + (size_t)l * NE * DIM * FFD, e_b1 + (size_t)l * NE * FFD, hb, ib, c * 256);
            ffn2_kernel<<<dim3(272, 4), 256, 0, stream>>>(
                hb, e_w2 + (size_t)l * NE * FFD * DIM, e_b2 + (size_t)l * NE * DIM, sob, ib, c * 256);
        }
        moe_gather<<<TOK, 64, 0, stream>>>(xb, sob, gv, ib);
    }

    pool1<<<dim3(8, 32), 256, 0, stream>>>(xb, pp);
    pool2<<<8, 256, 0, stream>>>(pp, pool);
    head_kernel<<<4, 256, 0, stream>>>(pool, head_w, head_b, out);
}